// Round 7
// baseline (697.470 us; speedup 1.0000x reference)
//
#include <hip/hip_runtime.h>

#define NC 91
#define NB 32
#define HW (1024 * 1024)

#define THREADS 256
#define PPT 64                          // pixels per thread
#define PIX_PER_BLOCK (THREADS * PPT)   // 16384
#define CHUNKS (HW / PIX_PER_BLOCK)     // 64 blocks per batch
#define NCOPY 8                         // histogram sub-copies (copy = lane&7)

// Round-7: FUSED single worker kernel (hist core identical to round 4, the
// fastest so far at ~102 us). Motivation: total dur_us ~284 vs hist dispatch
// ~107 — a constant ~175 us lives OUTSIDE the profiled dispatches in every
// round. This round removes the separate finalize dispatch (and keeps one
// tiny memset) to discriminate per-dispatch overhead vs fixed harness cost.
//
// Finalize-in-kernel: after the per-block global-atomic epilogue, block
// tid0 does an acq_rel agent-scope fetch_add on done[b]; the block seeing
// old==CHUNKS-1 is the LAST for batch b (no dispatch-order assumption, no
// spinning -> no deadlock) and computes out[b], reading the accumulators
// with agent-scope atomic loads (safe across non-coherent per-XCD L2s).
//
// DS-floor note (rounds 2-6): lane-divergent LDS traffic retires at
// ~2.2 lanes/cyc plain / ~1.1 atomic irrespective of bank conflicts, so any
// LDS histogram is floored at ~100 us for 2 lane-updates/pixel. Hist core
// left untouched this round for clean attribution.

__device__ __forceinline__ void proc_pixel(int x, int t, int* hp, int* s_inter) {
    atomicAdd(&hp[x], x == t ? 2 : 1);   // cnt_x + cnt_t contribution
    if (x != t) atomicAdd(&hp[t], 1);
    else        atomicAdd(&s_inter[x], 1);
}

__global__ __launch_bounds__(256, 8) void fused_kernel(const int* __restrict__ x,
                                                       const int* __restrict__ t,
                                                       int* __restrict__ g_hist,
                                                       int* __restrict__ g_inter,
                                                       int* __restrict__ done,
                                                       const float* __restrict__ smooth,
                                                       float* __restrict__ out) {
    __shared__ int s_h[NCOPY * NC];   // 728 words = 2912 B
    __shared__ int s_inter[NC];
    __shared__ int s_last;

    const int tid = threadIdx.x;
    for (int j = tid; j < NCOPY * NC; j += THREADS) s_h[j] = 0;
    if (tid < NC) s_inter[tid] = 0;
    __syncthreads();

    int* hp = &s_h[(tid & 7) * NC];

    const int b = blockIdx.y;
    const long base = (long)b * HW + (long)blockIdx.x * PIX_PER_BLOCK;
    const int4* __restrict__ x4 = (const int4*)(x + base);
    const int4* __restrict__ t4 = (const int4*)(t + base);

    const int n = PPT / 4;   // 16 iterations, 4 pixels each
    int4 xv0 = x4[tid],           tv0 = t4[tid];
    int4 xv1 = x4[THREADS + tid], tv1 = t4[THREADS + tid];

    for (int i = 0; i < n; ++i) {
        const int pf = (i + 2 < n) ? (i + 2) : (n - 1);   // clamped prefetch
        int4 xn = x4[pf * THREADS + tid];
        int4 tn = t4[pf * THREADS + tid];

        proc_pixel(xv0.x, tv0.x, hp, s_inter);
        proc_pixel(xv0.y, tv0.y, hp, s_inter);
        proc_pixel(xv0.z, tv0.z, hp, s_inter);
        proc_pixel(xv0.w, tv0.w, hp, s_inter);

        xv0 = xv1; tv0 = tv1;
        xv1 = xn;  tv1 = tn;
    }
    __syncthreads();

    // Per-block epilogue: fold 8 copies, one global atomic per class.
    if (tid < NC) {
        int sum = 0;
#pragma unroll
        for (int k = 0; k < NCOPY; ++k) sum += s_h[k * NC + tid];
        if (sum) atomicAdd(&g_hist[b * NC + tid], sum);   // cnt_x + cnt_t
        const int in = s_inter[tid];
        if (in)  atomicAdd(&g_inter[b * NC + tid], in);
    }
    __syncthreads();          // all lanes' epilogue atomics issued (barrier drains vmcnt)
    __threadfence();          // order them before the completion signal

    if (tid == 0) {
        int old = __hip_atomic_fetch_add(&done[b], 1, __ATOMIC_ACQ_REL,
                                         __HIP_MEMORY_SCOPE_AGENT);
        s_last = (old == CHUNKS - 1) ? 1 : 0;
    }
    __syncthreads();
    if (!s_last) return;

    // Last block of batch b: finalize (first wave only).
    if (tid < 64) {
        const float s = smooth[0];
        float acc = 0.0f;
        for (int c = tid; c < NC; c += 64) {
            int in = __hip_atomic_load(&g_inter[b * NC + c], __ATOMIC_RELAXED,
                                       __HIP_MEMORY_SCOPE_AGENT);
            int ht = __hip_atomic_load(&g_hist[b * NC + c], __ATOMIC_RELAXED,
                                       __HIP_MEMORY_SCOPE_AGENT);
            // union = cnt_x + cnt_t - inter
            acc += ((float)in + s) / ((float)(ht - in) + s);
        }
#pragma unroll
        for (int off = 32; off > 0; off >>= 1)
            acc += __shfl_down(acc, off, 64);
        if (tid == 0) out[b] = acc / (float)NC;
    }
}

extern "C" void kernel_launch(void* const* d_in, const int* in_sizes, int n_in,
                              void* d_out, int out_size, void* d_ws, size_t ws_size,
                              hipStream_t stream) {
    const int* x = (const int*)d_in[0];
    const int* t = (const int*)d_in[1];
    const float* smooth = (const float*)d_in[2];
    float* out = (float*)d_out;

    int* g_hist = (int*)d_ws;                 // NB*NC
    int* g_inter = g_hist + NB * NC;          // NB*NC
    int* done = g_inter + NB * NC;            // NB

    hipMemsetAsync(d_ws, 0, (2 * NB * NC + NB) * sizeof(int), stream);

    dim3 grid(CHUNKS, NB);  // 64 x 32 = 2048 blocks
    fused_kernel<<<grid, THREADS, 0, stream>>>(x, t, g_hist, g_inter, done,
                                               smooth, out);
}